// Round 1
// baseline (182.437 us; speedup 1.0000x reference)
//
#include <hip/hip_runtime.h>
#include <math.h>

// Problem constants (from reference setup_inputs): bases [1,4,136,200] f32,
// box_feat [N,789] f32 (col0 = image idx, 1:5 = box, 5: = 4*14*14 coeffs),
// output [N,544,800] f32.
#define OUTD 56
#define COD  14
#define BH   136
#define BW   200
#define IMGH 544
#define IMGW 800
#define BB   4
#define BFS  789   // 5 + 4*14*14

// ---------------------------------------------------------------------------
// Kernel 1: build the N 56x56 sigmoid masks into workspace.
// One block per roi; 256 threads grid-stride over the 3136 mask pixels.
// roi_align (aligned=True, sampling_ratio=1) + 14->56 bilinear coeff upsample
// (edge-clamped, matching jax.image.resize weight normalization) + softmax
// over the 4 bases + dot + sigmoid.
// ---------------------------------------------------------------------------
__global__ __launch_bounds__(256) void mask_kernel(
    const float* __restrict__ bases,
    const float* __restrict__ box_feat,
    float* __restrict__ masks) {
  const int n = blockIdx.x;
  const float* bf = box_feat + (size_t)n * BFS;
  const int bidx = (int)bf[0];
  const float x0 = bf[1], y0 = bf[2], x1 = bf[3], y1 = bf[4];
  // scaled box (SCALE=0.25, aligned=True -> -0.5)
  const float sx0 = x0 * 0.25f - 0.5f;
  const float sy0 = y0 * 0.25f - 0.5f;
  const float bw = (x1 - x0) * 0.25f * (1.0f / OUTD);
  const float bh = (y1 - y0) * 0.25f * (1.0f / OUTD);
  const float* feat = bases + (size_t)bidx * BB * BH * BW;
  const float* top  = bf + 5;

  for (int p = threadIdx.x; p < OUTD * OUTD; p += blockDim.x) {
    const int y = p / OUTD;
    const int x = p - y * OUTD;

    // ---- roi_align sample coordinates ----
    const float ysv = sy0 + ((float)y + 0.5f) * bh;
    const float xsv = sx0 + ((float)x + 0.5f) * bw;
    const float valid =
        (ysv >= -1.0f && ysv <= (float)BH && xsv >= -1.0f && xsv <= (float)BW)
            ? 1.0f : 0.0f;
    const float yc = fminf(fmaxf(ysv, 0.0f), (float)(BH - 1));
    const float xc = fminf(fmaxf(xsv, 0.0f), (float)(BW - 1));
    int yl = (int)floorf(yc); yl = yl > (BH - 2) ? (BH - 2) : yl;   // yc>=0
    int xl = (int)floorf(xc); xl = xl > (BW - 2) ? (BW - 2) : xl;
    const float ly = yc - (float)yl, hy = 1.0f - ly;
    const float lx = xc - (float)xl, hx = 1.0f - lx;
    const float w00 = hy * hx, w01 = hy * lx, w10 = ly * hx, w11 = ly * lx;

    // ---- coeff 14->56 bilinear upsample coordinates (edge clamp) ----
    float cyf = fminf(fmaxf(((float)y + 0.5f) * 0.25f - 0.5f, 0.0f), (float)(COD - 1));
    float cxf = fminf(fmaxf(((float)x + 0.5f) * 0.25f - 0.5f, 0.0f), (float)(COD - 1));
    int cyl = (int)floorf(cyf); cyl = cyl > (COD - 2) ? (COD - 2) : cyl;
    int cxl = (int)floorf(cxf); cxl = cxl > (COD - 2) ? (COD - 2) : cxl;
    const float cly = cyf - (float)cyl, chy = 1.0f - cly;
    const float clx = cxf - (float)cxl, chx = 1.0f - clx;
    const float cw00 = chy * chx, cw01 = chy * clx, cw10 = cly * chx, cw11 = cly * clx;

    float rvals[BB], cvals[BB];
#pragma unroll
    for (int b = 0; b < BB; ++b) {
      const float* fb = feat + b * BH * BW;
      const float r = w00 * fb[yl * BW + xl]       + w01 * fb[yl * BW + xl + 1] +
                      w10 * fb[(yl + 1) * BW + xl] + w11 * fb[(yl + 1) * BW + xl + 1];
      rvals[b] = r * valid;
      const float* tb = top + b * COD * COD;
      cvals[b] = cw00 * tb[cyl * COD + cxl]       + cw01 * tb[cyl * COD + cxl + 1] +
                 cw10 * tb[(cyl + 1) * COD + cxl] + cw11 * tb[(cyl + 1) * COD + cxl + 1];
    }

    // softmax over the 4 bases, blend, sigmoid
    const float mx = fmaxf(fmaxf(cvals[0], cvals[1]), fmaxf(cvals[2], cvals[3]));
    float e[BB], s = 0.0f;
#pragma unroll
    for (int b = 0; b < BB; ++b) { e[b] = __expf(cvals[b] - mx); s += e[b]; }
    const float inv = 1.0f / s;
    float dot = 0.0f;
#pragma unroll
    for (int b = 0; b < BB; ++b) dot += rvals[b] * (e[b] * inv);
    const float mval = 1.0f / (1.0f + __expf(-dot));

    masks[(size_t)n * (OUTD * OUTD) + p] = mval;
  }
}

// ---------------------------------------------------------------------------
// Kernel 2: paste masks to the full image. One thread per float4 of output.
// The separable tent-weight einsum pair == zero-padded bilinear gather of the
// 56x56 mask at (fy, fx). Early-out stores zeros when outside tent support.
// ---------------------------------------------------------------------------
__global__ __launch_bounds__(256) void paste_kernel(
    const float* __restrict__ masks,
    const float* __restrict__ box_feat,
    float4* __restrict__ out, int total4) {
  const int t = blockIdx.x * blockDim.x + threadIdx.x;
  if (t >= total4) return;
  const int per_n = IMGH * (IMGW / 4);
  const int n   = t / per_n;
  const int rem = t - n * per_n;
  const int h   = rem / (IMGW / 4);
  const int q4  = rem - h * (IMGW / 4);

  const float* bf = box_feat + (size_t)n * BFS;
  const float x0 = bf[1], y0 = bf[2], x1 = bf[3], y1 = bf[4];

  const float fy = ((float)h + 0.5f - y0) * ((float)OUTD / (y1 - y0)) - 0.5f;

  float4 o = make_float4(0.0f, 0.0f, 0.0f, 0.0f);
  if (fy > -1.0f && fy < (float)OUTD) {
    const int ml = (int)floorf(fy);
    const float wy1 = fy - (float)ml;
    const float wy0 = 1.0f - wy1;
    const float* mk = masks + (size_t)n * (OUTD * OUTD);
    const bool r0v = (ml >= 0);
    const bool r1v = (ml + 1 <= OUTD - 1);
    const float* row0 = mk + (r0v ? ml : 0) * OUTD;
    const float* row1 = mk + (r1v ? (ml + 1) : 0) * OUTD;
    const float invw = (float)OUTD / (x1 - x0);

    float res[4];
#pragma unroll
    for (int i = 0; i < 4; ++i) {
      const int q = q4 * 4 + i;
      const float fx = ((float)q + 0.5f - x0) * invw - 0.5f;
      float v = 0.0f;
      if (fx > -1.0f && fx < (float)OUTD) {
        const int xl = (int)floorf(fx);
        const float wx1 = fx - (float)xl;
        const float wx0 = 1.0f - wx1;
        const bool xlv = (xl >= 0);
        const bool xhv = (xl + 1 <= OUTD - 1);
        const int xls = xlv ? xl : 0;
        const int xhs = xhv ? (xl + 1) : 0;
        float v00 = (r0v && xlv) ? row0[xls] : 0.0f;
        float v01 = (r0v && xhv) ? row0[xhs] : 0.0f;
        float v10 = (r1v && xlv) ? row1[xls] : 0.0f;
        float v11 = (r1v && xhv) ? row1[xhs] : 0.0f;
        v = wy0 * (wx0 * v00 + wx1 * v01) + wy1 * (wx0 * v10 + wx1 * v11);
      }
      res[i] = v;
    }
    o = make_float4(res[0], res[1], res[2], res[3]);
  }
  out[t] = o;
}

extern "C" void kernel_launch(void* const* d_in, const int* in_sizes, int n_in,
                              void* d_out, int out_size, void* d_ws, size_t ws_size,
                              hipStream_t stream) {
  const float* bases    = (const float*)d_in[0];
  const float* box_feat = (const float*)d_in[1];
  const int N = in_sizes[1] / BFS;

  float* masks = (float*)d_ws;  // N*56*56 floats = 1.25 MB for N=100

  mask_kernel<<<N, 256, 0, stream>>>(bases, box_feat, masks);

  const int total4 = N * IMGH * (IMGW / 4);
  const int blocks = (total4 + 255) / 256;
  paste_kernel<<<blocks, 256, 0, stream>>>(masks, box_feat, (float4*)d_out, total4);
}